// Round 1
// baseline (671.254 us; speedup 1.0000x reference)
//
#include <hip/hip_runtime.h>
#include <hip/hip_bf16.h>

#define DIMC 512
#define BATCH 4
#define SEQ 4096
#define NHEAD 8
#define HD 64
#define M_TOK (BATCH*SEQ)   // 16384
#define N_QKV (3*DIMC)      // 1536

#define TILE 64
#define BK 16

static __device__ __forceinline__ float bf2f(unsigned short u) {
    union { unsigned int i; float f; } x; x.i = ((unsigned int)u) << 16; return x.f;
}
static __device__ __forceinline__ unsigned short f2bf(float f) {
    union { float f; unsigned int i; } x; x.f = f;
    unsigned int r = x.i + 0x7FFFu + ((x.i >> 16) & 1u);
    return (unsigned short)(r >> 16);
}

// Y1[m][o] = sum_c X[m][c] * W[o][c] + bias[o], stored bf16.
__global__ __launch_bounds__(256) void gemm_qkv(
    const float* __restrict__ A,    // [16384][512] fp32
    const float* __restrict__ W,    // [1536][512]  fp32
    const float* __restrict__ bias, // [1536]
    unsigned short* __restrict__ Y) // [16384][1536] bf16
{
    __shared__ float As[BK][TILE + 1];
    __shared__ float Bs[BK][TILE + 1];
    const int K = DIMC, N = N_QKV;
    const int tid = threadIdx.x;
    const int m0 = blockIdx.x * TILE;
    const int n0 = blockIdx.y * TILE;
    const int lr = tid >> 2;          // 0..63 row within tile
    const int lc = (tid & 3) << 2;    // 0,4,8,12 k-offset
    const int tm = (tid >> 4) << 2;   // 0..60
    const int tn = (tid & 15) << 2;   // 0..60
    float acc[4][4] = {};
    const float* Aptr = A + (size_t)(m0 + lr) * K + lc;
    const float* Wptr = W + (size_t)(n0 + lr) * K + lc;
    for (int k0 = 0; k0 < K; k0 += BK) {
        float4 a4 = *(const float4*)(Aptr + k0);
        float4 b4 = *(const float4*)(Wptr + k0);
        As[lc + 0][lr] = a4.x; As[lc + 1][lr] = a4.y;
        As[lc + 2][lr] = a4.z; As[lc + 3][lr] = a4.w;
        Bs[lc + 0][lr] = b4.x; Bs[lc + 1][lr] = b4.y;
        Bs[lc + 2][lr] = b4.z; Bs[lc + 3][lr] = b4.w;
        __syncthreads();
        #pragma unroll
        for (int kk = 0; kk < BK; ++kk) {
            float a[4], b[4];
            #pragma unroll
            for (int i = 0; i < 4; ++i) a[i] = As[kk][tm + i];
            #pragma unroll
            for (int j = 0; j < 4; ++j) b[j] = Bs[kk][tn + j];
            #pragma unroll
            for (int i = 0; i < 4; ++i)
                #pragma unroll
                for (int j = 0; j < 4; ++j)
                    acc[i][j] = fmaf(a[i], b[j], acc[i][j]);
        }
        __syncthreads();
    }
    #pragma unroll
    for (int i = 0; i < 4; ++i) {
        ushort4 o;
        o.x = f2bf(acc[i][0] + bias[n0 + tn + 0]);
        o.y = f2bf(acc[i][1] + bias[n0 + tn + 1]);
        o.z = f2bf(acc[i][2] + bias[n0 + tn + 2]);
        o.w = f2bf(acc[i][3] + bias[n0 + tn + 3]);
        *(ushort4*)(Y + (size_t)(m0 + tm + i) * N + n0 + tn) = o;
    }
}

// Per-token 8x8 head-mix attention. One wave = 8 tokens.
// Writes Y2 in the scrambled layout: y[b][h*512 + (n>>3)][(n&7)*64 + d].
__global__ __launch_bounds__(64) void attn_mix(
    const unsigned short* __restrict__ Y1, // [16384][1536] bf16
    unsigned short* __restrict__ Y2)       // [16384][512]  bf16 (scrambled)
{
    __shared__ float s[8 * 1540];   // 8 tokens, row stride 1540 (pad 4 -> PV conflict-free)
    const int t = threadIdx.x;
    const size_t base = (size_t)blockIdx.x * 8 * N_QKV;
    // cooperative load: 12288 bf16, 8 per thread per iter, coalesced
    #pragma unroll
    for (int i = 0; i < 24; ++i) {
        int v = i * 64 + t;
        int off = v * 8;
        int row = off / N_QKV;
        int col = off - row * N_QKV;
        ushort4 u0 = *(const ushort4*)(Y1 + base + off);
        ushort4 u1 = *(const ushort4*)(Y1 + base + off + 4);
        float* d = s + row * 1540 + col;
        d[0] = bf2f(u0.x); d[1] = bf2f(u0.y); d[2] = bf2f(u0.z); d[3] = bf2f(u0.w);
        d[4] = bf2f(u1.x); d[5] = bf2f(u1.y); d[6] = bf2f(u1.z); d[7] = bf2f(u1.w);
    }
    __syncthreads();
    const int tok = t >> 3, h = t & 7;
    const float* qp = s + tok * 1540 + h * HD;
    const float* kp = s + tok * 1540 + DIMC;
    const float* vp = s + tok * 1540 + 2 * DIMC;
    float sc[8];
    #pragma unroll
    for (int g = 0; g < 8; ++g) {
        float a = 0.f;
        const float* kg = kp + g * HD;
        #pragma unroll
        for (int i = 0; i < HD; ++i) {
            int d = (i + t) & 63;   // lane-rotated: breaks 64-stride bank aliasing
            a = fmaf(qp[d], kg[d], a);
        }
        sc[g] = a * 0.125f;
    }
    float mx = sc[0];
    #pragma unroll
    for (int g = 1; g < 8; ++g) mx = fmaxf(mx, sc[g]);
    float sum = 0.f;
    #pragma unroll
    for (int g = 0; g < 8; ++g) { sc[g] = __expf(sc[g] - mx); sum += sc[g]; }
    float inv = 1.f / sum;
    #pragma unroll
    for (int g = 0; g < 8; ++g) sc[g] *= inv;

    const int tokg = blockIdx.x * 8 + tok;
    const int n = tokg & (SEQ - 1);
    const int b = tokg >> 12;
    const size_t drow = (size_t)b * SEQ + h * 512 + (n >> 3);
    unsigned short* dst = Y2 + drow * DIMC + ((n & 7) << 6);
    #pragma unroll
    for (int d0 = 0; d0 < HD; d0 += 8) {
        float o[8];
        #pragma unroll
        for (int j = 0; j < 8; ++j) {
            float a = 0.f;
            #pragma unroll
            for (int g = 0; g < 8; ++g)
                a = fmaf(sc[g], vp[g * HD + d0 + j], a);  // broadcast across h-lanes
            o[j] = a;
        }
        ushort4 o0, o1;
        o0.x = f2bf(o[0]); o0.y = f2bf(o[1]); o0.z = f2bf(o[2]); o0.w = f2bf(o[3]);
        o1.x = f2bf(o[4]); o1.y = f2bf(o[5]); o1.z = f2bf(o[6]); o1.w = f2bf(o[7]);
        *(ushort4*)(dst + d0) = o0;
        *(ushort4*)(dst + d0 + 4) = o1;
    }
}

// C[m][o] = sum_c Y2[m][c] * W[o][c] + bias[o], fp32 out.
__global__ __launch_bounds__(256) void gemm_out(
    const unsigned short* __restrict__ A,  // [16384][512] bf16
    const float* __restrict__ W,           // [512][512]
    const float* __restrict__ bias,        // [512]
    float* __restrict__ C)                 // [16384][512] fp32
{
    __shared__ float As[BK][TILE + 1];
    __shared__ float Bs[BK][TILE + 1];
    const int K = DIMC, N = DIMC;
    const int tid = threadIdx.x;
    const int m0 = blockIdx.x * TILE;
    const int n0 = blockIdx.y * TILE;
    const int lr = tid >> 2;
    const int lc = (tid & 3) << 2;
    const int tm = (tid >> 4) << 2;
    const int tn = (tid & 15) << 2;
    float acc[4][4] = {};
    const unsigned short* Aptr = A + (size_t)(m0 + lr) * K + lc;
    const float* Wptr = W + (size_t)(n0 + lr) * K + lc;
    for (int k0 = 0; k0 < K; k0 += BK) {
        ushort4 a4 = *(const ushort4*)(Aptr + k0);
        float4 b4 = *(const float4*)(Wptr + k0);
        As[lc + 0][lr] = bf2f(a4.x); As[lc + 1][lr] = bf2f(a4.y);
        As[lc + 2][lr] = bf2f(a4.z); As[lc + 3][lr] = bf2f(a4.w);
        Bs[lc + 0][lr] = b4.x; Bs[lc + 1][lr] = b4.y;
        Bs[lc + 2][lr] = b4.z; Bs[lc + 3][lr] = b4.w;
        __syncthreads();
        #pragma unroll
        for (int kk = 0; kk < BK; ++kk) {
            float a[4], b[4];
            #pragma unroll
            for (int i = 0; i < 4; ++i) a[i] = As[kk][tm + i];
            #pragma unroll
            for (int j = 0; j < 4; ++j) b[j] = Bs[kk][tn + j];
            #pragma unroll
            for (int i = 0; i < 4; ++i)
                #pragma unroll
                for (int j = 0; j < 4; ++j)
                    acc[i][j] = fmaf(a[i], b[j], acc[i][j]);
        }
        __syncthreads();
    }
    #pragma unroll
    for (int i = 0; i < 4; ++i) {
        float4 o;
        o.x = acc[i][0] + bias[n0 + tn + 0];
        o.y = acc[i][1] + bias[n0 + tn + 1];
        o.z = acc[i][2] + bias[n0 + tn + 2];
        o.w = acc[i][3] + bias[n0 + tn + 3];
        *(float4*)(C + (size_t)(m0 + tm + i) * N + n0 + tn) = o;
    }
}

extern "C" void kernel_launch(void* const* d_in, const int* in_sizes, int n_in,
                              void* d_out, int out_size, void* d_ws, size_t ws_size,
                              hipStream_t stream) {
    const float* x     = (const float*)d_in[0];
    const float* qkv_w = (const float*)d_in[1];
    const float* qkv_b = (const float*)d_in[2];
    const float* out_w = (const float*)d_in[3];
    const float* out_b = (const float*)d_in[4];
    float* out = (float*)d_out;

    unsigned short* Y1 = (unsigned short*)d_ws;            // 16384*1536 bf16 = 50.3 MB
    unsigned short* Y2 = Y1 + (size_t)M_TOK * N_QKV;       // 16384*512  bf16 = 16.8 MB

    gemm_qkv<<<dim3(M_TOK / TILE, N_QKV / TILE), 256, 0, stream>>>(x, qkv_w, qkv_b, Y1);
    attn_mix<<<dim3(M_TOK / 8), 64, 0, stream>>>(Y1, Y2);
    gemm_out<<<dim3(M_TOK / TILE, DIMC / TILE), 256, 0, stream>>>(Y2, out_w, out_b, out);
}

// Round 2
// 105.207 us; speedup vs baseline: 6.3803x; 6.3803x over previous
//
#include <hip/hip_runtime.h>
#include <hip/hip_bf16.h>

#define DIMC 512
#define BATCH 4
#define SEQ 4096
#define NHEAD 8
#define HD 64
#define M_TOK (BATCH*SEQ)   // 16384
#define N_QKV (3*DIMC)      // 1536

typedef __bf16 bfv8 __attribute__((ext_vector_type(8)));
typedef float f32v4 __attribute__((ext_vector_type(4)));
typedef unsigned short u16v8 __attribute__((ext_vector_type(8)));

static __device__ __forceinline__ float bf2f(unsigned short u) {
    union { unsigned int i; float f; } x; x.i = ((unsigned int)u) << 16; return x.f;
}
static __device__ __forceinline__ unsigned short f2bf(float f) {
    union { float f; unsigned int i; } x; x.f = f;
    unsigned int r = x.i + 0x7FFFu + ((x.i >> 16) & 1u);
    return (unsigned short)(r >> 16);
}

static __device__ __forceinline__ void gload_lds16(const void* g, void* s) {
    __builtin_amdgcn_global_load_lds(
        (const __attribute__((address_space(1))) unsigned int*)g,
        (__attribute__((address_space(3))) unsigned int*)s, 16, 0, 0);
}

// ---------------- fp32 -> bf16 conversion ----------------
__global__ __launch_bounds__(256) void cvt_f32_bf16(
    const float* __restrict__ in, unsigned short* __restrict__ out, int n8)
{
    int i = blockIdx.x * blockDim.x + threadIdx.x;
    if (i >= n8) return;
    const float4* p = (const float4*)in + (size_t)i * 2;
    float4 a = p[0], b = p[1];
    u16v8 o;
    o[0] = f2bf(a.x); o[1] = f2bf(a.y); o[2] = f2bf(a.z); o[3] = f2bf(a.w);
    o[4] = f2bf(b.x); o[5] = f2bf(b.y); o[6] = f2bf(b.z); o[7] = f2bf(b.w);
    *(u16v8*)(out + (size_t)i * 8) = o;
}

// ---------------- MFMA NT GEMM: C[M][N] = A[M][K] * B[N][K]^T + bias -------
// m97 structure: 128x128 tile, BK=32, 4 waves (2x2), 4x4 16x16x32 frags/wave,
// global_load_lds width-16 staging, 2 barriers per K-step.
template<bool OUT_BF16>
__global__ __launch_bounds__(256) void gemm_nt_mfma(
    const unsigned short* __restrict__ A,  // [M][K] bf16
    const unsigned short* __restrict__ B,  // [N][K] bf16
    const float* __restrict__ bias,        // [N]
    void* __restrict__ Cout,
    int M, int N, int K)
{
    __shared__ __align__(16) unsigned short As[128 * 32];
    __shared__ __align__(16) unsigned short Bs[128 * 32];
    const int tid  = threadIdx.x;
    const int lane = tid & 63;
    const int wid  = tid >> 6;        // 0..3
    const int wm   = wid >> 1;        // 0..1
    const int wn   = wid & 1;         // 0..1
    const int m0 = blockIdx.x * 128;
    const int n0 = blockIdx.y * 128;

    f32v4 acc[4][4] = {};

    // staging: chunk = wid*128 + j*64 + lane covers 8 bf16 at
    // row = chunk>>2, kcol = (chunk&3)*8 of the 128x32 tile
    const int c0 = wid * 128 + lane;
    const int c1 = c0 + 64;
    const unsigned short* aSrc0 = A + (size_t)(m0 + (c0 >> 2)) * K + (c0 & 3) * 8;
    const unsigned short* aSrc1 = A + (size_t)(m0 + (c1 >> 2)) * K + (c1 & 3) * 8;
    const unsigned short* bSrc0 = B + (size_t)(n0 + (c0 >> 2)) * K + (c0 & 3) * 8;
    const unsigned short* bSrc1 = B + (size_t)(n0 + (c1 >> 2)) * K + (c1 & 3) * 8;
    unsigned short* aDst0 = As + wid * 1024;        // wave-uniform LDS base
    unsigned short* aDst1 = As + wid * 1024 + 512;
    unsigned short* bDst0 = Bs + wid * 1024;
    unsigned short* bDst1 = Bs + wid * 1024 + 512;

    const int frow = lane & 15;
    const int fk   = (lane >> 4) * 8;

    for (int k0 = 0; k0 < K; k0 += 32) {
        gload_lds16(aSrc0 + k0, aDst0);
        gload_lds16(aSrc1 + k0, aDst1);
        gload_lds16(bSrc0 + k0, bDst0);
        gload_lds16(bSrc1 + k0, bDst1);
        __syncthreads();
        bfv8 af[4], bfr[4];
        #pragma unroll
        for (int i = 0; i < 4; ++i) {
            af[i]  = *(const bfv8*)(As + (wm * 64 + i * 16 + frow) * 32 + fk);
            bfr[i] = *(const bfv8*)(Bs + (wn * 64 + i * 16 + frow) * 32 + fk);
        }
        #pragma unroll
        for (int i = 0; i < 4; ++i)
            #pragma unroll
            for (int j = 0; j < 4; ++j)
                acc[i][j] = __builtin_amdgcn_mfma_f32_16x16x32_bf16(
                    af[i], bfr[j], acc[i][j], 0, 0, 0);
        __syncthreads();
    }

    // epilogue: D row = (lane>>4)*4 + r, col = lane&15  [m89-verified]
    const int erow = (lane >> 4) * 4;
    const int ecol = lane & 15;
    #pragma unroll
    for (int j = 0; j < 4; ++j) {
        const int col = n0 + wn * 64 + j * 16 + ecol;
        const float bv = bias[col];
        #pragma unroll
        for (int i = 0; i < 4; ++i) {
            const int rbase = m0 + wm * 64 + i * 16 + erow;
            #pragma unroll
            for (int r = 0; r < 4; ++r) {
                const float v = acc[i][j][r] + bv;
                if constexpr (OUT_BF16)
                    ((unsigned short*)Cout)[(size_t)(rbase + r) * N + col] = f2bf(v);
                else
                    ((float*)Cout)[(size_t)(rbase + r) * N + col] = v;
            }
        }
    }
}

// ---------------- per-token 8x8 head-mix attention ----------------
// Writes Y2 scrambled: y[b][h*512 + (n>>3)][(n&7)*64 + d] so gemm_out is plain NT.
__global__ __launch_bounds__(64) void attn_mix(
    const unsigned short* __restrict__ Y1, // [16384][1536] bf16
    unsigned short* __restrict__ Y2)       // [16384][512]  bf16 (scrambled)
{
    __shared__ float s[8 * 1540];
    const int t = threadIdx.x;
    const size_t base = (size_t)blockIdx.x * 8 * N_QKV;
    #pragma unroll
    for (int i = 0; i < 24; ++i) {
        int v = i * 64 + t;
        int off = v * 8;
        int row = off / N_QKV;
        int col = off - row * N_QKV;
        ushort4 u0 = *(const ushort4*)(Y1 + base + off);
        ushort4 u1 = *(const ushort4*)(Y1 + base + off + 4);
        float* d = s + row * 1540 + col;
        d[0] = bf2f(u0.x); d[1] = bf2f(u0.y); d[2] = bf2f(u0.z); d[3] = bf2f(u0.w);
        d[4] = bf2f(u1.x); d[5] = bf2f(u1.y); d[6] = bf2f(u1.z); d[7] = bf2f(u1.w);
    }
    __syncthreads();
    const int tok = t >> 3, h = t & 7;
    const float* qp = s + tok * 1540 + h * HD;
    const float* kp = s + tok * 1540 + DIMC;
    const float* vp = s + tok * 1540 + 2 * DIMC;
    float sc[8];
    #pragma unroll
    for (int g = 0; g < 8; ++g) {
        float a = 0.f;
        const float* kg = kp + g * HD;
        #pragma unroll
        for (int i = 0; i < HD; ++i) {
            int d = (i + t) & 63;
            a = fmaf(qp[d], kg[d], a);
        }
        sc[g] = a * 0.125f;
    }
    float mx = sc[0];
    #pragma unroll
    for (int g = 1; g < 8; ++g) mx = fmaxf(mx, sc[g]);
    float sum = 0.f;
    #pragma unroll
    for (int g = 0; g < 8; ++g) { sc[g] = __expf(sc[g] - mx); sum += sc[g]; }
    float inv = 1.f / sum;
    #pragma unroll
    for (int g = 0; g < 8; ++g) sc[g] *= inv;

    const int tokg = blockIdx.x * 8 + tok;
    const int n = tokg & (SEQ - 1);
    const int b = tokg >> 12;
    const size_t drow = (size_t)b * SEQ + h * 512 + (n >> 3);
    unsigned short* dst = Y2 + drow * DIMC + ((n & 7) << 6);
    #pragma unroll
    for (int d0 = 0; d0 < HD; d0 += 8) {
        float o[8];
        #pragma unroll
        for (int j = 0; j < 8; ++j) {
            float a = 0.f;
            #pragma unroll
            for (int g = 0; g < 8; ++g)
                a = fmaf(sc[g], vp[g * HD + d0 + j], a);
            o[j] = a;
        }
        ushort4 o0, o1;
        o0.x = f2bf(o[0]); o0.y = f2bf(o[1]); o0.z = f2bf(o[2]); o0.w = f2bf(o[3]);
        o1.x = f2bf(o[4]); o1.y = f2bf(o[5]); o1.z = f2bf(o[6]); o1.w = f2bf(o[7]);
        *(ushort4*)(dst + d0) = o0;
        *(ushort4*)(dst + d0 + 4) = o1;
    }
}

extern "C" void kernel_launch(void* const* d_in, const int* in_sizes, int n_in,
                              void* d_out, int out_size, void* d_ws, size_t ws_size,
                              hipStream_t stream) {
    const float* x     = (const float*)d_in[0];
    const float* qkv_w = (const float*)d_in[1];
    const float* qkv_b = (const float*)d_in[2];
    const float* out_w = (const float*)d_in[3];
    const float* out_b = (const float*)d_in[4];
    float* out = (float*)d_out;

    // workspace layout (bytes):
    //   [0,   50.3M) Y1  bf16 16384x1536
    //   [50.3M, 67.1M) Xb bf16 16384x512  -- later reused as Y2 (lifetimes disjoint)
    //   [67.1M, 68.7M) Wq bf16 1536x512
    //   [68.7M, 69.2M) Wo bf16 512x512
    unsigned short* Y1 = (unsigned short*)d_ws;
    unsigned short* Xb = Y1 + (size_t)M_TOK * N_QKV;
    unsigned short* Y2 = Xb;   // overlay: Xb dead before attn_mix writes Y2
    unsigned short* Wq = Xb + (size_t)M_TOK * DIMC;
    unsigned short* Wo = Wq + (size_t)N_QKV * DIMC;

    cvt_f32_bf16<<<(M_TOK * DIMC / 8 + 255) / 256, 256, 0, stream>>>(x, Xb, M_TOK * DIMC / 8);
    cvt_f32_bf16<<<(N_QKV * DIMC / 8 + 255) / 256, 256, 0, stream>>>(qkv_w, Wq, N_QKV * DIMC / 8);
    cvt_f32_bf16<<<(DIMC * DIMC / 8 + 255) / 256, 256, 0, stream>>>(out_w, Wo, DIMC * DIMC / 8);

    gemm_nt_mfma<true><<<dim3(M_TOK / 128, N_QKV / 128), 256, 0, stream>>>(
        Xb, Wq, qkv_b, Y1, M_TOK, N_QKV, DIMC);

    attn_mix<<<dim3(M_TOK / 8), 64, 0, stream>>>(Y1, Y2);

    gemm_nt_mfma<false><<<dim3(M_TOK / 128, DIMC / 128), 256, 0, stream>>>(
        Y2, Wo, out_b, out, M_TOK, DIMC, DIMC);
}